// Round 12
// baseline (466.520 us; speedup 1.0000x reference)
//
#include <hip/hip_runtime.h>
#include <math.h>

// GCN: h = elu(D^-1/2 (A+I) D^-1/2 (h W) + b [+ resid])
// N=100000 nodes, E=1600000 edges, 128 features per layer.
//
// R19 == R18 with the lane-mapping bug fixed (R18: lb=(h<<7)+l*16 spans
// the FULL 256B row -> h=1 lanes 8-15 read/write the next node's row,
// absmax 1.55). Correct half-split: lane owns 4 features = 8 bytes,
// lb = h*128 + l*8; gathers dwordx2; acch[2]; 4-feature epilogue.
//
// Theory (unchanged from R18): aggregate is BANDWIDTH-limited at ~4TB/s
// (R15->R17: outstanding reqs 96->160 at equal bytes -> no gain). XCD
// feature-half shard halves per-XCD table footprint: XCDs 0-3 touch only
// bytes [0,128) of each row, XCDs 4-7 bytes [128,256) => table fetch
// 205->102MB. Edge loop keeps R17's low-VALU structure (own-entry
// metadata + in-quarter shfl, 8 gathers in flight).
// Fallback (pre-committed): if agg >= 62us with FETCH ~145MB, the
// limiter is gather issue rate itself -> revert R15, declare roofline.

#define NFEAT 128
#define LDSP 136   // LDS row pitch in shorts (128 + 8 pad)
#define BSH 9      // bucket shift: 512 nodes/bucket
#define BWID 512

typedef short short8 __attribute__((ext_vector_type(8)));
typedef unsigned short ushort8 __attribute__((ext_vector_type(8)));
typedef _Float16 half8 __attribute__((ext_vector_type(8)));
typedef _Float16 h16x2 __attribute__((ext_vector_type(2)));
typedef float f32x4 __attribute__((ext_vector_type(4)));
typedef float f32x2 __attribute__((ext_vector_type(2)));
typedef int i32x4 __attribute__((ext_vector_type(4)));
typedef int i32x2 __attribute__((ext_vector_type(2)));

static __device__ __forceinline__ unsigned short f2bf(float f) {
  union { float f; unsigned int u; } v; v.f = f;
  unsigned int r = v.u + 0x7fffu + ((v.u >> 16) & 1u);  // RNE (finite values)
  return (unsigned short)(r >> 16);
}
static __device__ __forceinline__ unsigned short f2h(float f) {
  union { _Float16 h; unsigned short u; } c; c.h = (_Float16)f; return c.u;
}
static __device__ __forceinline__ h16x2 u2h2(unsigned int u) {
  union { unsigned int i; h16x2 h; } c; c.i = u; return c.h;
}
static __device__ __forceinline__ float elu_fast(float a) {
  return a > 0.0f ? a : (__expf(a) - 1.0f);
}

// ---------------- GEMM body, fp32 input -> bf16 MFMA, f16 out (L0) ----
static __device__ __forceinline__ void gemm_body(
    int gblk, const float* __restrict__ h, const unsigned short* __restrict__ Wt,
    unsigned short* __restrict__ out, int n, unsigned short* lds) {
  int t = threadIdx.x;
  int block0 = gblk * 64;

  const f32x4* h4 = (const f32x4*)h;
  #pragma unroll
  for (int i = 0; i < 8; ++i) {
    int idx = t + 256 * i;          // 0..2047
    int r = idx >> 5, c = idx & 31; // row, float4-col
    int grow = block0 + r; if (grow >= n) grow = n - 1;
    f32x4 v = __builtin_nontemporal_load(&h4[(size_t)grow * 32 + c]);
    ushort4 b;
    b.x = f2bf(v.x); b.y = f2bf(v.y); b.z = f2bf(v.z); b.w = f2bf(v.w);
    *(ushort4*)&lds[r * LDSP + c * 4] = b;
  }
  __syncthreads();

  int lane = t & 63, wave = t >> 6;
  int row16 = lane & 15;
  int kgrp = lane >> 4;

  short8 afrag[4];
  #pragma unroll
  for (int ks = 0; ks < 4; ++ks)
    afrag[ks] =
        *(const short8*)&lds[(wave * 16 + row16) * LDSP + ks * 32 + kgrp * 8];

  f32x4 acc[8];
  #pragma unroll
  for (int ct = 0; ct < 8; ++ct) {
    acc[ct] = (f32x4){0.0f, 0.0f, 0.0f, 0.0f};
    const short8* wrow =
        (const short8*)(Wt + (size_t)(ct * 16 + row16) * NFEAT);
    #pragma unroll
    for (int ks = 0; ks < 4; ++ks) {
      acc[ct] = __builtin_amdgcn_mfma_f32_16x16x32_bf16(
          wrow[ks * 4 + kgrp], afrag[ks], acc[ct], 0, 0, 0);
    }
  }

  int orow = block0 + wave * 16 + row16;
  if (orow < n) {
    unsigned short* op = out + (size_t)orow * NFEAT + kgrp * 4;
    #pragma unroll
    for (int ct = 0; ct < 8; ++ct) {
      ushort4 o;
      o.x = f2h(acc[ct][0]); o.y = f2h(acc[ct][1]);
      o.z = f2h(acc[ct][2]); o.w = f2h(acc[ct][3]);
      *(ushort4*)(op + ct * 16) = o;
    }
  }
}

// ---------------- GEMM, f16 input -> f16 MFMA, f16 out (L1, L2) -------
__global__ __launch_bounds__(256) void gemm_f16_kernel(
    const unsigned short* __restrict__ h16,  // f16 bits [n][128]
    const unsigned short* __restrict__ Wt,   // f16 bits [128][128] (n-major)
    unsigned short* __restrict__ out, int n) {
  __shared__ int lds_i[64 * LDSP / 2];
  unsigned short* lds = (unsigned short*)lds_i;
  int t = threadIdx.x;
  int block0 = blockIdx.x * 64;

  const ushort8* h8 = (const ushort8*)h16;
  #pragma unroll
  for (int i = 0; i < 4; ++i) {
    int idx = t + 256 * i;          // 0..1023
    int r = idx >> 4, c = idx & 15; // row, 8-elem col
    int grow = block0 + r; if (grow >= n) grow = n - 1;
    ushort8 v = __builtin_nontemporal_load(&h8[(size_t)grow * 16 + c]);
    *(ushort8*)&lds[r * LDSP + c * 8] = v;
  }
  __syncthreads();

  int lane = t & 63, wave = t >> 6;
  int row16 = lane & 15;
  int kgrp = lane >> 4;

  half8 afrag[4];
  #pragma unroll
  for (int ks = 0; ks < 4; ++ks)
    afrag[ks] =
        *(const half8*)&lds[(wave * 16 + row16) * LDSP + ks * 32 + kgrp * 8];

  f32x4 acc[8];
  #pragma unroll
  for (int ct = 0; ct < 8; ++ct) {
    acc[ct] = (f32x4){0.0f, 0.0f, 0.0f, 0.0f};
    const half8* wrow =
        (const half8*)(Wt + (size_t)(ct * 16 + row16) * NFEAT);
    #pragma unroll
    for (int ks = 0; ks < 4; ++ks) {
      acc[ct] = __builtin_amdgcn_mfma_f32_16x16x32_f16(
          wrow[ks * 4 + kgrp], afrag[ks], acc[ct], 0, 0, 0);
    }
  }

  int orow = block0 + wave * 16 + row16;
  if (orow < n) {
    unsigned short* op = out + (size_t)orow * NFEAT + kgrp * 4;
    #pragma unroll
    for (int ct = 0; ct < 8; ++ct) {
      ushort4 o;
      o.x = f2h(acc[ct][0]); o.y = f2h(acc[ct][1]);
      o.z = f2h(acc[ct][2]); o.w = f2h(acc[ct][3]);
      *(ushort4*)(op + ct * 16) = o;
    }
  }
}

// gemm0 fused with Pass A (bucket histogram) — independent work.
__global__ __launch_bounds__(256) void fused_g0_hist_kernel(
    const float* __restrict__ x, const unsigned short* __restrict__ Wt0,
    unsigned short* __restrict__ hWb, int n, int gb,
    const int4* __restrict__ dst4, int* __restrict__ bcnt, int e4, int nbuc) {
  __shared__ int lds_i[64 * LDSP / 2];
  int t = threadIdx.x;
  if ((int)blockIdx.x < gb) {
    gemm_body(blockIdx.x, x, Wt0, hWb, n, (unsigned short*)lds_i);
  } else {
    int* hist = lds_i;
    hist[t] = 0;
    __syncthreads();
    int base = ((int)blockIdx.x - gb) * 1024;
    #pragma unroll
    for (int i = 0; i < 4; ++i) {
      int idx = base + t + 256 * i;
      if (idx < e4) {
        int4 d = dst4[idx];
        atomicAdd(&hist[d.x >> BSH], 1);
        atomicAdd(&hist[d.y >> BSH], 1);
        atomicAdd(&hist[d.z >> BSH], 1);
        atomicAdd(&hist[d.w >> BSH], 1);
      }
    }
    __syncthreads();
    int h = hist[t];
    if (t < nbuc && h) atomicAdd(&bcnt[t], h);
  }
}

// Pass B: exclusive scan of bucket counts (nbuc <= 256), init gcur, rowp[n]=E
__global__ __launch_bounds__(256) void scan_buckets_kernel(
    const int* __restrict__ bcnt, int* __restrict__ boff,
    int* __restrict__ gcur, int* __restrict__ rowp, int nbuc, int n, int e) {
  __shared__ int wsum[4];
  int t = threadIdx.x, lane = t & 63, wid = t >> 6;
  int v = (t < nbuc) ? bcnt[t] : 0;
  int s = v;
  #pragma unroll
  for (int off = 1; off < 64; off <<= 1) {
    int u = __shfl_up(s, off, 64);
    if (lane >= off) s += u;
  }
  if (lane == 63) wsum[wid] = s;
  __syncthreads();
  int add = 0;
  for (int w = 0; w < wid; ++w) add += wsum[w];
  int incl = add + s;
  if (t < nbuc) { boff[t] = incl - v; gcur[t] = incl - v; }
  if (t == nbuc - 1) boff[nbuc] = incl;  // == E
  if (t == 0) rowp[n] = e;
}

// Pass C: scatter (dst,src) u64 into bucket-major ebuf, block-chunked.
__global__ __launch_bounds__(256) void bucket_scatter_kernel(
    const int4* __restrict__ src4, const int4* __restrict__ dst4,
    int* __restrict__ gcur, unsigned long long* __restrict__ ebuf, int e4) {
  __shared__ int hist[256];
  __shared__ int cbase[256];
  __shared__ int cur[256];
  int t = threadIdx.x;
  hist[t] = 0; cur[t] = 0;
  __syncthreads();
  int base = blockIdx.x * 1024;
  int4 dv[4], sv[4];
  bool val[4];
  #pragma unroll
  for (int i = 0; i < 4; ++i) {
    int idx = base + t + 256 * i;
    val[i] = idx < e4;
    if (val[i]) {
      dv[i] = dst4[idx];
      sv[i] = src4[idx];
      atomicAdd(&hist[dv[i].x >> BSH], 1);
      atomicAdd(&hist[dv[i].y >> BSH], 1);
      atomicAdd(&hist[dv[i].z >> BSH], 1);
      atomicAdd(&hist[dv[i].w >> BSH], 1);
    }
  }
  __syncthreads();
  int h = hist[t];
  if (h) cbase[t] = atomicAdd(&gcur[t], h);  // hist[t]==0 for t>=nbuc
  __syncthreads();
  #pragma unroll
  for (int i = 0; i < 4; ++i) {
    if (val[i]) {
      int d, s, b, p;
      d = dv[i].x; s = sv[i].x; b = d >> BSH;
      p = cbase[b] + atomicAdd(&cur[b], 1);
      ebuf[p] = ((unsigned long long)(unsigned)d << 32) | (unsigned)s;
      d = dv[i].y; s = sv[i].y; b = d >> BSH;
      p = cbase[b] + atomicAdd(&cur[b], 1);
      ebuf[p] = ((unsigned long long)(unsigned)d << 32) | (unsigned)s;
      d = dv[i].z; s = sv[i].z; b = d >> BSH;
      p = cbase[b] + atomicAdd(&cur[b], 1);
      ebuf[p] = ((unsigned long long)(unsigned)d << 32) | (unsigned)s;
      d = dv[i].w; s = sv[i].w; b = d >> BSH;
      p = cbase[b] + atomicAdd(&cur[b], 1);
      ebuf[p] = ((unsigned long long)(unsigned)d << 32) | (unsigned)s;
    }
  }
}

// Pass D1: per-bucket degree hist (LDS) + local scan -> rowp, dinv.
__global__ __launch_bounds__(256) void bucket_deg_kernel(
    const unsigned long long* __restrict__ ebuf, const int* __restrict__ boff,
    int* __restrict__ rowp, float* __restrict__ dinv, int n) {
  __shared__ int deg[BWID];
  __shared__ int wsum[4];
  int t = threadIdx.x;
  int b = blockIdx.x, node0 = b << BSH;
  deg[t] = 0; deg[t + 256] = 0;
  __syncthreads();
  int ebeg = boff[b], eend = boff[b + 1];
  for (int i = ebeg + t; i < eend; i += 256) {
    int d = (int)(ebuf[i] >> 32);
    atomicAdd(&deg[d - node0], 1);
  }
  __syncthreads();
  int d0 = deg[2 * t], d1 = deg[2 * t + 1];
  int s = d0 + d1;
  int lane = t & 63, wid = t >> 6;
  int sc = s;
  #pragma unroll
  for (int off = 1; off < 64; off <<= 1) {
    int u = __shfl_up(sc, off, 64);
    if (lane >= off) sc += u;
  }
  if (lane == 63) wsum[wid] = sc;
  __syncthreads();
  int add = 0;
  for (int w = 0; w < wid; ++w) add += wsum[w];
  int excl = ebeg + add + sc - s;  // rowp of node 2t in this bucket
  int node = node0 + 2 * t;
  if (node < n) {
    rowp[node] = excl;
    dinv[node] = rsqrtf(1.0f + (float)d0);
  }
  if (node + 1 < n) {
    rowp[node + 1] = excl + d0;
    dinv[node + 1] = rsqrtf(1.0f + (float)d1);
  }
}

// Pass D2: per-bucket fine scatter into colw (u32: s<<15 | wq).
__global__ __launch_bounds__(256) void bucket_fill_kernel(
    const unsigned long long* __restrict__ ebuf, const int* __restrict__ boff,
    const int* __restrict__ rowp, const float* __restrict__ dinv,
    unsigned int* __restrict__ colw, int n) {
  __shared__ int cur[BWID];
  int t = threadIdx.x;
  int b = blockIdx.x, node0 = b << BSH;
  for (int k = t; k < BWID; k += 256) {
    int node = node0 + k;
    cur[k] = (node < n) ? rowp[node] : 0;
  }
  __syncthreads();
  int ebeg = boff[b], eend = boff[b + 1];
  for (int i = ebeg + t; i < eend; i += 256) {
    unsigned long long p = ebuf[i];
    int d = (int)(p >> 32);
    int s = (int)(unsigned int)p;
    float w = dinv[s] * dinv[d];
    unsigned int wq = (unsigned int)(w * 32767.0f + 0.5f);
    int pos = atomicAdd(&cur[d - node0], 1);
    colw[pos] = ((unsigned int)s << 15) | wq;
  }
}

// W fp32 [k][n] -> Wt0 bf16 [n][k]; Wt1/Wt2 f16 [n][k]
__global__ __launch_bounds__(256) void wprep_kernel(
    const float* __restrict__ W0, const float* __restrict__ W1,
    const float* __restrict__ W2, unsigned short* __restrict__ Wt0,
    unsigned short* __restrict__ Wt1, unsigned short* __restrict__ Wt2) {
  int which = blockIdx.x >> 6;
  int i = (blockIdx.x & 63) * 256 + threadIdx.x;
  int nn = i >> 7, k = i & 127;
  const float* W = which == 0 ? W0 : (which == 1 ? W1 : W2);
  float v = W[k * 128 + nn];
  if (which == 0) {
    Wt0[nn * 128 + k] = f2bf(v);
  } else {
    (which == 1 ? Wt1 : Wt2)[nn * 128 + k] = f2h(v);
  }
}

// ------- Aggregate (quarter-per-node, XCD-sharded feature halves) -----
// Block = 16 nodes x ONE 64-feature half; (blockIdx>>2)&1 selects half
// (blockIdx%8 round-robins XCDs -> XCDs 0-3 touch bytes [0,128), XCDs
// 4-7 bytes [128,256) of every row; per-XCD table footprint halves).
// 16-lane quarter per node; lane l owns 4 features = 8 BYTES:
// lb = h*128 + l*8. Per 16-edge chunk: lane loads ITS colw entry (4B
// coalesced), unpacks once, distributes via in-quarter __shfl; 8 dwordx2
// gathers issued back-to-back. No cross-lane reduce.
// mode 0: out f16. 1: +resid f16. 2: out f32 (final).
__global__ __launch_bounds__(256) void aggregate_kernel(
    const unsigned short* __restrict__ hWb, const int* __restrict__ row_ptr,
    const unsigned int* __restrict__ colw, const float* __restrict__ dinv,
    const float* __restrict__ bias, const unsigned int* __restrict__ resid16,
    void* __restrict__ out, int n, int mode) {
  int bi = blockIdx.x;
  int h = (bi >> 2) & 1;                 // XCD 0-3 -> half 0, 4-7 -> half 1
  int ng = (bi >> 3) * 4 + (bi & 3);     // bijective node-group (4 | NB)
  int t = threadIdx.x;
  int lane = t & 63;
  int qb = lane & 48;       // quarter base lane (q*16)
  int l = lane & 15;        // lane within quarter
  int node = ng * 16 + (t >> 6) * 4 + (qb >> 4);
  bool active = node < n;
  int nc = active ? node : n - 1;
  int beg = row_ptr[nc];
  int end = active ? row_ptr[nc + 1] : beg;
  int cnt = end - beg;
  int lb = (h << 7) + (l << 3);  // byte offset within a 256B row (8B/lane)
  const char* hWbc = (const char*)hWb;
  const float WQI = 1.0f / 32767.0f;

  // hoisted epilogue loads (independent of the gather stream)
  i32x2 sv = *(const i32x2*)(hWbc + (size_t)nc * 256 + (unsigned)lb);
  f32x4 bv = ((const f32x4*)bias)[(h << 4) + l];
  i32x2 rv = (i32x2){0, 0};
  if (mode >= 1) {
    rv = __builtin_nontemporal_load(
        (const i32x2*)((const char*)resid16 + (size_t)nc * 256 + (unsigned)lb));
  }
  float di = dinv[nc];

  h16x2 acch[2];
  acch[0] = (h16x2){(_Float16)0.0f, (_Float16)0.0f};
  acch[1] = (h16x2){(_Float16)0.0f, (_Float16)0.0f};

  for (int cb = 0; __any(cb < cnt); cb += 16) {
    // coalesced metadata: lane l loads entry cb+l of its quarter's list
    int myidx = beg + cb + l;
    unsigned int pk = 0;                 // invalid lanes: row 0, w=0
    if (myidx < end) pk = __builtin_nontemporal_load(&colw[myidx]);
    unsigned int bo = (pk >> 15) << 8;   // src row byte offset
    float wv = (float)(pk & 0x7fffu) * WQI;
    unsigned int wh = f2h(wv);
    unsigned int wpk = (wh << 16) | wh;

    if (cb < cnt) {   // quarter-uniform: whole quarters take this branch
      #pragma unroll
      for (int g = 0; g < 2; ++g) {
        unsigned int bj[8], wj[8];
        #pragma unroll
        for (int j = 0; j < 8; ++j) {
          bj[j] = (unsigned int)__shfl((int)bo, qb + g * 8 + j, 64);
          wj[j] = (unsigned int)__shfl((int)wpk, qb + g * 8 + j, 64);
        }
        // 8 independent dwordx2 gathers, issued back-to-back
        i32x2 pv[8];
        #pragma unroll
        for (int j = 0; j < 8; ++j)
          pv[j] = *(const i32x2*)(hWbc + (bj[j] + (unsigned int)lb));
        #pragma unroll
        for (int j = 0; j < 8; ++j) {
          h16x2 hw = u2h2(wj[j]);
          acch[0] += hw * u2h2((unsigned int)pv[j][0]);
          acch[1] += hw * u2h2((unsigned int)pv[j][1]);
        }
      }
    }
  }

  // epilogue: 4 features per lane, no cross-lane traffic at all
  float dii = di * di;
  float f[4];
  {
    h16x2 s0 = u2h2((unsigned int)sv[0]);
    h16x2 s1 = u2h2((unsigned int)sv[1]);
    h16x2 r0 = u2h2((unsigned int)rv[0]);
    h16x2 r1 = u2h2((unsigned int)rv[1]);
    f[0] = (float)acch[0].x + dii * (float)s0.x + (float)r0.x + bv[0];
    f[1] = (float)acch[0].y + dii * (float)s0.y + (float)r0.y + bv[1];
    f[2] = (float)acch[1].x + dii * (float)s1.x + (float)r1.x + bv[2];
    f[3] = (float)acch[1].y + dii * (float)s1.y + (float)r1.y + bv[3];
  }
  #pragma unroll
  for (int k = 0; k < 4; ++k) f[k] = elu_fast(f[k]);

  if (active) {
    if (mode == 2) {
      f32x4 o = (f32x4){f[0], f[1], f[2], f[3]};
      __builtin_nontemporal_store(
          o, (f32x4*)((float*)out + (size_t)node * 128 +
                      (unsigned)((h << 6) + l * 4)));
    } else {
      i32x2 ov;
      ov[0] = (int)(((unsigned)f2h(f[1]) << 16) | f2h(f[0]));
      ov[1] = (int)(((unsigned)f2h(f[3]) << 16) | f2h(f[2]));
      __builtin_nontemporal_store(
          ov, (i32x2*)((char*)out + (size_t)node * 256 + (unsigned)lb));
    }
  }
}

extern "C" void kernel_launch(void* const* d_in, const int* in_sizes, int n_in,
                              void* d_out, int out_size, void* d_ws, size_t ws_size,
                              hipStream_t stream) {
  const float* x  = (const float*)d_in[0];
  const int* eidx = (const int*)d_in[1];
  const float* W0 = (const float*)d_in[2];
  const float* b0 = (const float*)d_in[3];
  const float* W1 = (const float*)d_in[4];
  const float* b1 = (const float*)d_in[5];
  const float* W2 = (const float*)d_in[6];
  const float* b2 = (const float*)d_in[7];
  float* outp = (float*)d_out;

  const int N = in_sizes[0] / NFEAT;   // 100000
  const int E = in_sizes[1] / 2;       // 1600000 (divisible by 4)
  const int* src = eidx;
  const int* dst = eidx + E;
  const int NBUC = (N + BWID - 1) >> BSH;  // 196
  const int e4 = E / 4;

  // workspace layout (all chunk sizes 1KB-multiples)
  const size_t S1 = 401408;                   // > (N+1)*4
  const size_t SBK = 1024;                    // > (NBUC+1)*4
  const size_t SW = 32768;                    // 128*128*2
  const size_t SE = (size_t)E * 4;            // 6.4 MB colw u32
  const size_t SEB = (size_t)E * 8;           // 12.8 MB bucketed (dst,src)
  const size_t SH = (size_t)N * NFEAT * 2;    // 25.6 MB f16 features
  char* p = (char*)d_ws;
  float* dinv   = (float*)p;            p += S1;
  int*   rowp   = (int*)p;              p += S1;
  int*   bcnt   = (int*)p;              p += SBK;
  int*   boff   = (int*)p;              p += SBK;
  int*   gcur   = (int*)p;              p += SBK;
  unsigned short* Wt0 = (unsigned short*)p;  p += SW;  // bf16
  unsigned short* Wt1 = (unsigned short*)p;  p += SW;  // f16
  unsigned short* Wt2 = (unsigned short*)p;  p += SW;  // f16
  unsigned int* colw = (unsigned int*)p; p += SE;
  unsigned long long* ebuf = (unsigned long long*)p; p += SEB;
  unsigned short* hWb = (unsigned short*)p;  p += SH;  // f16 gather table
  unsigned short* hA  = (unsigned short*)p;  p += SH;  // f16 h
  unsigned short* hB  = (unsigned short*)p;  p += SH;  // f16 h

  int gemm_blocks = (N + 63) / 64;        // 1563
  int cbk = (e4 + 1023) / 1024;           // 391 (4096 edges/block)
  int NB = (N + 15) / 16;                 // node-groups of 16 nodes
  NB = (NB + 3) & ~3;                     // bijection needs 4 | NB
  int agg_blocks = 2 * NB;                // x2 feature halves

  // ---- prep + fused {gemm0, Pass A} ----
  wprep_kernel<<<192, 256, 0, stream>>>(W0, W1, W2, Wt0, Wt1, Wt2);
  hipMemsetAsync(bcnt, 0, (size_t)NBUC * 4, stream);
  fused_g0_hist_kernel<<<gemm_blocks + cbk, 256, 0, stream>>>(
      x, Wt0, hWb, N, gemm_blocks, (const int4*)dst, bcnt, e4, NBUC);

  // ---- bucketed CSR build ----
  scan_buckets_kernel<<<1, 256, 0, stream>>>(bcnt, boff, gcur, rowp,
                                             NBUC, N, E);
  bucket_scatter_kernel<<<cbk, 256, 0, stream>>>(
      (const int4*)src, (const int4*)dst, gcur, ebuf, e4);
  bucket_deg_kernel<<<NBUC, 256, 0, stream>>>(ebuf, boff, rowp, dinv, N);
  bucket_fill_kernel<<<NBUC, 256, 0, stream>>>(ebuf, boff, rowp, dinv,
                                               colw, N);

  // ---- layer 0 aggregate (gemm0 already done): out hA f16 ----
  aggregate_kernel<<<agg_blocks, 256, 0, stream>>>(
      hWb, rowp, colw, dinv, b0, nullptr, hA, N, 0);
  // ---- layer 1 ----
  gemm_f16_kernel<<<gemm_blocks, 256, 0, stream>>>(hA, Wt1, hWb, N);
  aggregate_kernel<<<agg_blocks, 256, 0, stream>>>(
      hWb, rowp, colw, dinv, b1, (const unsigned int*)hA, hB, N, 1);
  // ---- layer 2, write d_out f32 ----
  gemm_f16_kernel<<<gemm_blocks, 256, 0, stream>>>(hB, Wt2, hWb, N);
  aggregate_kernel<<<agg_blocks, 256, 0, stream>>>(
      hWb, rowp, colw, dinv, b2, (const unsigned int*)hB, outp, N, 2);
}

// Round 13
// 448.615 us; speedup vs baseline: 1.0399x; 1.0399x over previous
//
#include <hip/hip_runtime.h>
#include <math.h>

// GCN: h = elu(D^-1/2 (A+I) D^-1/2 (h W) + b [+ resid])
// N=100000 nodes, E=1600000 edges, 128 features per layer.
//
// R20 == R15 restored (best measured: 449.6us, agg 64.4us), plus the
// bcnt memset folded into wprep (-1 dispatch, zero risk).
//
// Why revert: 12 rounds of evidence say the aggregate is pinned at
// ~64us = 257MB @ 4.0 TB/s, the empirical ceiling for its random-256B
// row-gather + stream mix. Falsified levers: VMEM instr count (R8),
// MLP 96->160 outstanding (R9/R17), byte cut via XCD shard (R10, R19 --
// bytes fell exactly as predicted, duration ROSE: request-pattern
// efficiency dominates bytes), per-edge VALU (R14), epilogue VALU (R15,
// -9us VALU -> -0.8us), request amplification (R16). fp8 table fails
// the error budget (2^-4 x sqrt(17) ~ 0.06 > 0.028 threshold).
// Composite roofline: 205MB compulsory cross-XCD table fetch @ ~4TB/s
// pattern rate + 51MB streams @ 6.3 => ~59us; R15 is within ~9%.

#define NFEAT 128
#define LDSP 136   // LDS row pitch in shorts (128 + 8 pad)
#define BSH 9      // bucket shift: 512 nodes/bucket
#define BWID 512

typedef short short8 __attribute__((ext_vector_type(8)));
typedef unsigned short ushort8 __attribute__((ext_vector_type(8)));
typedef _Float16 half8 __attribute__((ext_vector_type(8)));
typedef _Float16 h16x2 __attribute__((ext_vector_type(2)));
typedef float f32x4 __attribute__((ext_vector_type(4)));
typedef float f32x2 __attribute__((ext_vector_type(2)));
typedef int i32x4 __attribute__((ext_vector_type(4)));

static __device__ __forceinline__ unsigned short f2bf(float f) {
  union { float f; unsigned int u; } v; v.f = f;
  unsigned int r = v.u + 0x7fffu + ((v.u >> 16) & 1u);  // RNE (finite values)
  return (unsigned short)(r >> 16);
}
static __device__ __forceinline__ unsigned short f2h(float f) {
  union { _Float16 h; unsigned short u; } c; c.h = (_Float16)f; return c.u;
}
static __device__ __forceinline__ h16x2 u2h2(int u) {
  union { int i; h16x2 h; } c; c.i = u; return c.h;
}
static __device__ __forceinline__ int h22u(h16x2 h) {
  union { h16x2 h; int i; } c; c.h = h; return c.i;
}
static __device__ __forceinline__ float elu_fast(float a) {
  return a > 0.0f ? a : (__expf(a) - 1.0f);
}

// ---------------- GEMM body, fp32 input -> bf16 MFMA, f16 out (L0) ----
static __device__ __forceinline__ void gemm_body(
    int gblk, const float* __restrict__ h, const unsigned short* __restrict__ Wt,
    unsigned short* __restrict__ out, int n, unsigned short* lds) {
  int t = threadIdx.x;
  int block0 = gblk * 64;

  const f32x4* h4 = (const f32x4*)h;
  #pragma unroll
  for (int i = 0; i < 8; ++i) {
    int idx = t + 256 * i;          // 0..2047
    int r = idx >> 5, c = idx & 31; // row, float4-col
    int grow = block0 + r; if (grow >= n) grow = n - 1;
    f32x4 v = __builtin_nontemporal_load(&h4[(size_t)grow * 32 + c]);
    ushort4 b;
    b.x = f2bf(v.x); b.y = f2bf(v.y); b.z = f2bf(v.z); b.w = f2bf(v.w);
    *(ushort4*)&lds[r * LDSP + c * 4] = b;
  }
  __syncthreads();

  int lane = t & 63, wave = t >> 6;
  int row16 = lane & 15;
  int kgrp = lane >> 4;

  short8 afrag[4];
  #pragma unroll
  for (int ks = 0; ks < 4; ++ks)
    afrag[ks] =
        *(const short8*)&lds[(wave * 16 + row16) * LDSP + ks * 32 + kgrp * 8];

  f32x4 acc[8];
  #pragma unroll
  for (int ct = 0; ct < 8; ++ct) {
    acc[ct] = (f32x4){0.0f, 0.0f, 0.0f, 0.0f};
    const short8* wrow =
        (const short8*)(Wt + (size_t)(ct * 16 + row16) * NFEAT);
    #pragma unroll
    for (int ks = 0; ks < 4; ++ks) {
      acc[ct] = __builtin_amdgcn_mfma_f32_16x16x32_bf16(
          wrow[ks * 4 + kgrp], afrag[ks], acc[ct], 0, 0, 0);
    }
  }

  int orow = block0 + wave * 16 + row16;
  if (orow < n) {
    unsigned short* op = out + (size_t)orow * NFEAT + kgrp * 4;
    #pragma unroll
    for (int ct = 0; ct < 8; ++ct) {
      ushort4 o;
      o.x = f2h(acc[ct][0]); o.y = f2h(acc[ct][1]);
      o.z = f2h(acc[ct][2]); o.w = f2h(acc[ct][3]);
      *(ushort4*)(op + ct * 16) = o;
    }
  }
}

// ---------------- GEMM, f16 input -> f16 MFMA, f16 out (L1, L2) -------
__global__ __launch_bounds__(256) void gemm_f16_kernel(
    const unsigned short* __restrict__ h16,  // f16 bits [n][128]
    const unsigned short* __restrict__ Wt,   // f16 bits [128][128] (n-major)
    unsigned short* __restrict__ out, int n) {
  __shared__ int lds_i[64 * LDSP / 2];
  unsigned short* lds = (unsigned short*)lds_i;
  int t = threadIdx.x;
  int block0 = blockIdx.x * 64;

  const ushort8* h8 = (const ushort8*)h16;
  #pragma unroll
  for (int i = 0; i < 4; ++i) {
    int idx = t + 256 * i;          // 0..1023
    int r = idx >> 4, c = idx & 15; // row, 8-elem col
    int grow = block0 + r; if (grow >= n) grow = n - 1;
    ushort8 v = __builtin_nontemporal_load(&h8[(size_t)grow * 16 + c]);
    *(ushort8*)&lds[r * LDSP + c * 8] = v;
  }
  __syncthreads();

  int lane = t & 63, wave = t >> 6;
  int row16 = lane & 15;
  int kgrp = lane >> 4;

  half8 afrag[4];
  #pragma unroll
  for (int ks = 0; ks < 4; ++ks)
    afrag[ks] =
        *(const half8*)&lds[(wave * 16 + row16) * LDSP + ks * 32 + kgrp * 8];

  f32x4 acc[8];
  #pragma unroll
  for (int ct = 0; ct < 8; ++ct) {
    acc[ct] = (f32x4){0.0f, 0.0f, 0.0f, 0.0f};
    const half8* wrow =
        (const half8*)(Wt + (size_t)(ct * 16 + row16) * NFEAT);
    #pragma unroll
    for (int ks = 0; ks < 4; ++ks) {
      acc[ct] = __builtin_amdgcn_mfma_f32_16x16x32_f16(
          wrow[ks * 4 + kgrp], afrag[ks], acc[ct], 0, 0, 0);
    }
  }

  int orow = block0 + wave * 16 + row16;
  if (orow < n) {
    unsigned short* op = out + (size_t)orow * NFEAT + kgrp * 4;
    #pragma unroll
    for (int ct = 0; ct < 8; ++ct) {
      ushort4 o;
      o.x = f2h(acc[ct][0]); o.y = f2h(acc[ct][1]);
      o.z = f2h(acc[ct][2]); o.w = f2h(acc[ct][3]);
      *(ushort4*)(op + ct * 16) = o;
    }
  }
}

// gemm0 fused with Pass A (bucket histogram) — independent work.
__global__ __launch_bounds__(256) void fused_g0_hist_kernel(
    const float* __restrict__ x, const unsigned short* __restrict__ Wt0,
    unsigned short* __restrict__ hWb, int n, int gb,
    const int4* __restrict__ dst4, int* __restrict__ bcnt, int e4, int nbuc) {
  __shared__ int lds_i[64 * LDSP / 2];
  int t = threadIdx.x;
  if ((int)blockIdx.x < gb) {
    gemm_body(blockIdx.x, x, Wt0, hWb, n, (unsigned short*)lds_i);
  } else {
    int* hist = lds_i;
    hist[t] = 0;
    __syncthreads();
    int base = ((int)blockIdx.x - gb) * 1024;
    #pragma unroll
    for (int i = 0; i < 4; ++i) {
      int idx = base + t + 256 * i;
      if (idx < e4) {
        int4 d = dst4[idx];
        atomicAdd(&hist[d.x >> BSH], 1);
        atomicAdd(&hist[d.y >> BSH], 1);
        atomicAdd(&hist[d.z >> BSH], 1);
        atomicAdd(&hist[d.w >> BSH], 1);
      }
    }
    __syncthreads();
    int h = hist[t];
    if (t < nbuc && h) atomicAdd(&bcnt[t], h);
  }
}

// Pass B: exclusive scan of bucket counts (nbuc <= 256), init gcur, rowp[n]=E
__global__ __launch_bounds__(256) void scan_buckets_kernel(
    const int* __restrict__ bcnt, int* __restrict__ boff,
    int* __restrict__ gcur, int* __restrict__ rowp, int nbuc, int n, int e) {
  __shared__ int wsum[4];
  int t = threadIdx.x, lane = t & 63, wid = t >> 6;
  int v = (t < nbuc) ? bcnt[t] : 0;
  int s = v;
  #pragma unroll
  for (int off = 1; off < 64; off <<= 1) {
    int u = __shfl_up(s, off, 64);
    if (lane >= off) s += u;
  }
  if (lane == 63) wsum[wid] = s;
  __syncthreads();
  int add = 0;
  for (int w = 0; w < wid; ++w) add += wsum[w];
  int incl = add + s;
  if (t < nbuc) { boff[t] = incl - v; gcur[t] = incl - v; }
  if (t == nbuc - 1) boff[nbuc] = incl;  // == E
  if (t == 0) rowp[n] = e;
}

// Pass C: scatter (dst,src) u64 into bucket-major ebuf, block-chunked.
__global__ __launch_bounds__(256) void bucket_scatter_kernel(
    const int4* __restrict__ src4, const int4* __restrict__ dst4,
    int* __restrict__ gcur, unsigned long long* __restrict__ ebuf, int e4) {
  __shared__ int hist[256];
  __shared__ int cbase[256];
  __shared__ int cur[256];
  int t = threadIdx.x;
  hist[t] = 0; cur[t] = 0;
  __syncthreads();
  int base = blockIdx.x * 1024;
  int4 dv[4], sv[4];
  bool val[4];
  #pragma unroll
  for (int i = 0; i < 4; ++i) {
    int idx = base + t + 256 * i;
    val[i] = idx < e4;
    if (val[i]) {
      dv[i] = dst4[idx];
      sv[i] = src4[idx];
      atomicAdd(&hist[dv[i].x >> BSH], 1);
      atomicAdd(&hist[dv[i].y >> BSH], 1);
      atomicAdd(&hist[dv[i].z >> BSH], 1);
      atomicAdd(&hist[dv[i].w >> BSH], 1);
    }
  }
  __syncthreads();
  int h = hist[t];
  if (h) cbase[t] = atomicAdd(&gcur[t], h);  // hist[t]==0 for t>=nbuc
  __syncthreads();
  #pragma unroll
  for (int i = 0; i < 4; ++i) {
    if (val[i]) {
      int d, s, b, p;
      d = dv[i].x; s = sv[i].x; b = d >> BSH;
      p = cbase[b] + atomicAdd(&cur[b], 1);
      ebuf[p] = ((unsigned long long)(unsigned)d << 32) | (unsigned)s;
      d = dv[i].y; s = sv[i].y; b = d >> BSH;
      p = cbase[b] + atomicAdd(&cur[b], 1);
      ebuf[p] = ((unsigned long long)(unsigned)d << 32) | (unsigned)s;
      d = dv[i].z; s = sv[i].z; b = d >> BSH;
      p = cbase[b] + atomicAdd(&cur[b], 1);
      ebuf[p] = ((unsigned long long)(unsigned)d << 32) | (unsigned)s;
      d = dv[i].w; s = sv[i].w; b = d >> BSH;
      p = cbase[b] + atomicAdd(&cur[b], 1);
      ebuf[p] = ((unsigned long long)(unsigned)d << 32) | (unsigned)s;
    }
  }
}

// Pass D1: per-bucket degree hist (LDS) + local scan -> rowp, dinv.
__global__ __launch_bounds__(256) void bucket_deg_kernel(
    const unsigned long long* __restrict__ ebuf, const int* __restrict__ boff,
    int* __restrict__ rowp, float* __restrict__ dinv, int n) {
  __shared__ int deg[BWID];
  __shared__ int wsum[4];
  int t = threadIdx.x;
  int b = blockIdx.x, node0 = b << BSH;
  deg[t] = 0; deg[t + 256] = 0;
  __syncthreads();
  int ebeg = boff[b], eend = boff[b + 1];
  for (int i = ebeg + t; i < eend; i += 256) {
    int d = (int)(ebuf[i] >> 32);
    atomicAdd(&deg[d - node0], 1);
  }
  __syncthreads();
  int d0 = deg[2 * t], d1 = deg[2 * t + 1];
  int s = d0 + d1;
  int lane = t & 63, wid = t >> 6;
  int sc = s;
  #pragma unroll
  for (int off = 1; off < 64; off <<= 1) {
    int u = __shfl_up(sc, off, 64);
    if (lane >= off) sc += u;
  }
  if (lane == 63) wsum[wid] = sc;
  __syncthreads();
  int add = 0;
  for (int w = 0; w < wid; ++w) add += wsum[w];
  int excl = ebeg + add + sc - s;  // rowp of node 2t in this bucket
  int node = node0 + 2 * t;
  if (node < n) {
    rowp[node] = excl;
    dinv[node] = rsqrtf(1.0f + (float)d0);
  }
  if (node + 1 < n) {
    rowp[node + 1] = excl + d0;
    dinv[node + 1] = rsqrtf(1.0f + (float)d1);
  }
}

// Pass D2: per-bucket fine scatter into colw (writes confined to the
// bucket's ~32KB region -> one block/XCD -> L2 lines merge fully).
__global__ __launch_bounds__(256) void bucket_fill_kernel(
    const unsigned long long* __restrict__ ebuf, const int* __restrict__ boff,
    const int* __restrict__ rowp, const float* __restrict__ dinv,
    unsigned int* __restrict__ colw, int n) {
  __shared__ int cur[BWID];
  int t = threadIdx.x;
  int b = blockIdx.x, node0 = b << BSH;
  for (int k = t; k < BWID; k += 256) {
    int node = node0 + k;
    cur[k] = (node < n) ? rowp[node] : 0;
  }
  __syncthreads();
  int ebeg = boff[b], eend = boff[b + 1];
  for (int i = ebeg + t; i < eend; i += 256) {
    unsigned long long p = ebuf[i];
    int d = (int)(p >> 32);
    int s = (int)(unsigned int)p;
    float w = dinv[s] * dinv[d];
    unsigned int wq = (unsigned int)(w * 32767.0f + 0.5f);
    int pos = atomicAdd(&cur[d - node0], 1);
    colw[pos] = ((unsigned int)s << 15) | wq;
  }
}

// W fp32 [k][n] -> Wt0 bf16 [n][k]; Wt1/Wt2 f16 [n][k].
// Block 0 also zeroes bcnt (replaces the hipMemsetAsync dispatch; wprep
// fully precedes fused_g0_hist which is the first bcnt writer).
__global__ __launch_bounds__(256) void wprep_kernel(
    const float* __restrict__ W0, const float* __restrict__ W1,
    const float* __restrict__ W2, unsigned short* __restrict__ Wt0,
    unsigned short* __restrict__ Wt1, unsigned short* __restrict__ Wt2,
    int* __restrict__ bcnt) {
  if (blockIdx.x == 0) bcnt[threadIdx.x] = 0;   // 256 ints = full SBK
  int which = blockIdx.x >> 6;
  int i = (blockIdx.x & 63) * 256 + threadIdx.x;
  int nn = i >> 7, k = i & 127;
  const float* W = which == 0 ? W0 : (which == 1 ? W1 : W2);
  float v = W[k * 128 + nn];
  if (which == 0) {
    Wt0[nn * 128 + k] = f2bf(v);
  } else {
    (which == 1 ? Wt1 : Wt2)[nn * 128 + k] = f2h(v);
  }
}

// ---------------- Aggregate (f16 table, pk_fma_f16, packed reduce) ----
// One wave per node, quarter-split gathers. Full 16-edge steps issue 4
// independent dwordx4 gathers; the wave-uniform tail issues ceil(r/4).
// Accumulation: packed f16; quarter-reduce also packed f16 (shfl_xor on
// bits + v_pk_add_f16). ELU via v_exp_f32 (__expf), not libm expm1f.
// mode 0: out f16. 1: +resid f16. 2: out f32 (final).
__global__ __launch_bounds__(256) void aggregate_kernel(
    const unsigned short* __restrict__ hWb, const int* __restrict__ row_ptr,
    const unsigned int* __restrict__ colw, const float* __restrict__ dinv,
    const float* __restrict__ bias, const unsigned int* __restrict__ resid16,
    void* __restrict__ out, int n, int mode) {
  int node = blockIdx.x * 4 + (threadIdx.x >> 6);
  int lane = threadIdx.x & 63;
  if (node >= n) return;  // wave-uniform
  int q = lane >> 4;      // quarter: which edge of the 4-pack
  int l15 = lane & 15;
  int lb = l15 * 16;      // byte offset within a 256B row
  const char* hWbc = (const char*)hWb;
  int beg = row_ptr[node], end = row_ptr[node + 1];
  const float WQI = 1.0f / 32767.0f;

  // hoisted independent loads: self row word, bias, resid, dinv
  unsigned int su =
      *(const unsigned int*)(hWbc + (size_t)node * 256 + (unsigned)(lb + q * 4));
  f32x2 bv = ((const f32x2*)bias)[l15 * 4 + q];
  size_t oidx = (size_t)node * 64 + (unsigned)(l15 * 4 + q);
  float rx = 0.0f, ry = 0.0f;
  if (mode >= 1) {
    unsigned int rv = __builtin_nontemporal_load(&resid16[oidx]);
    h16x2 rh = u2h2((int)rv);
    rx = (float)rh.x; ry = (float)rh.y;
  }
  float di = dinv[node];

  h16x2 acch[4];
  #pragma unroll
  for (int m = 0; m < 4; ++m) acch[m] = (h16x2){(_Float16)0.0f, (_Float16)0.0f};

  for (int cbeg = beg; cbeg < end; cbeg += 64) {
    int cnt = end - cbeg; if (cnt > 64) cnt = 64;
    unsigned int pk = 0;                 // lanes >= cnt: row 0, weight 0
    if (lane < cnt) pk = __builtin_nontemporal_load(&colw[cbeg + lane]);
    unsigned int bo = (pk >> 15) << 8;   // row byte offset (s * 256)
    float wv = (float)(pk & 0x7fffu) * WQI;
    unsigned int wh = f2h(wv);
    int wpk = (int)((wh << 16) | wh);    // (w,w) half2

    int j = 0;
    for (; j + 16 <= cnt; j += 16) {
      unsigned int b0 = (unsigned int)__shfl((int)bo, j + 0 + q, 64);
      unsigned int b1 = (unsigned int)__shfl((int)bo, j + 4 + q, 64);
      unsigned int b2 = (unsigned int)__shfl((int)bo, j + 8 + q, 64);
      unsigned int b3 = (unsigned int)__shfl((int)bo, j + 12 + q, 64);
      int w0 = __shfl(wpk, j + 0 + q, 64);
      int w1 = __shfl(wpk, j + 4 + q, 64);
      int w2 = __shfl(wpk, j + 8 + q, 64);
      int w3 = __shfl(wpk, j + 12 + q, 64);
      // 4 independent gathers, issued back-to-back
      i32x4 p0 = *(const i32x4*)(hWbc + (b0 + (unsigned int)lb));
      i32x4 p1 = *(const i32x4*)(hWbc + (b1 + (unsigned int)lb));
      i32x4 p2 = *(const i32x4*)(hWbc + (b2 + (unsigned int)lb));
      i32x4 p3 = *(const i32x4*)(hWbc + (b3 + (unsigned int)lb));
      h16x2 h0 = u2h2(w0), h1 = u2h2(w1), h2 = u2h2(w2), h3 = u2h2(w3);
      #pragma unroll
      for (int m = 0; m < 4; ++m) acch[m] += h0 * u2h2(p0[m]);
      #pragma unroll
      for (int m = 0; m < 4; ++m) acch[m] += h1 * u2h2(p1[m]);
      #pragma unroll
      for (int m = 0; m < 4; ++m) acch[m] += h2 * u2h2(p2[m]);
      #pragma unroll
      for (int m = 0; m < 4; ++m) acch[m] += h3 * u2h2(p3[m]);
    }
    int r = cnt - j;  // 0..15, wave-uniform
    if (r > 0) {
      unsigned int bA, bB = 0, bC = 0, bD = 0;
      int wA, wB = 0, wC = 0, wD = 0;
      bA = (unsigned int)__shfl((int)bo, j + 0 + q, 64);
      wA = __shfl(wpk, j + 0 + q, 64);
      if (r > 4) {
        bB = (unsigned int)__shfl((int)bo, j + 4 + q, 64);
        wB = __shfl(wpk, j + 4 + q, 64);
      }
      if (r > 8) {
        bC = (unsigned int)__shfl((int)bo, j + 8 + q, 64);
        wC = __shfl(wpk, j + 8 + q, 64);
      }
      if (r > 12) {
        bD = (unsigned int)__shfl((int)bo, j + 12 + q, 64);
        wD = __shfl(wpk, j + 12 + q, 64);
      }
      i32x4 pA, pB, pC, pD;
      pA = *(const i32x4*)(hWbc + (bA + (unsigned int)lb));
      if (r > 4)  pB = *(const i32x4*)(hWbc + (bB + (unsigned int)lb));
      if (r > 8)  pC = *(const i32x4*)(hWbc + (bC + (unsigned int)lb));
      if (r > 12) pD = *(const i32x4*)(hWbc + (bD + (unsigned int)lb));
      h16x2 hA = u2h2(wA);
      #pragma unroll
      for (int m = 0; m < 4; ++m) acch[m] += hA * u2h2(pA[m]);
      if (r > 4) {
        h16x2 hB = u2h2(wB);
        #pragma unroll
        for (int m = 0; m < 4; ++m) acch[m] += hB * u2h2(pB[m]);
      }
      if (r > 8) {
        h16x2 hC = u2h2(wC);
        #pragma unroll
        for (int m = 0; m < 4; ++m) acch[m] += hC * u2h2(pC[m]);
      }
      if (r > 12) {
        h16x2 hD = u2h2(wD);
        #pragma unroll
        for (int m = 0; m < 4; ++m) acch[m] += hD * u2h2(pD[m]);
      }
    }
  }

  // quarter-reduce, packed f16: shfl_xor on bits + v_pk_add_f16
  #pragma unroll
  for (int m = 0; m < 4; ++m) {
    acch[m] += u2h2(__shfl_xor(h22u(acch[m]), 16, 64));
    acch[m] += u2h2(__shfl_xor(h22u(acch[m]), 32, 64));
  }

  // epilogue, all 64 lanes active: quarter q owns columns 2q, 2q+1 of
  // this lane's 8-column slice (= the two halves of acch[q])
  int own = h22u(acch[0]);
  #pragma unroll
  for (int k = 1; k < 4; ++k) {
    if (q == k) own = h22u(acch[k]);
  }
  h16x2 o2 = u2h2(own);
  float sx = (float)o2.x, sy = (float)o2.y;
  h16x2 sh = u2h2((int)su);
  float dii = di * di;
  float ax = sx + dii * (float)sh.x + bv.x + rx;
  float ay = sy + dii * (float)sh.y + bv.y + ry;
  float ox = elu_fast(ax);
  float oy = elu_fast(ay);
  if (mode == 2) {
    f32x2 o; o.x = ox; o.y = oy;
    __builtin_nontemporal_store(o, &((f32x2*)out)[oidx]);
  } else {
    unsigned int pk2 = ((unsigned int)f2h(oy) << 16) | f2h(ox);
    __builtin_nontemporal_store(pk2, &((unsigned int*)out)[oidx]);
  }
}

extern "C" void kernel_launch(void* const* d_in, const int* in_sizes, int n_in,
                              void* d_out, int out_size, void* d_ws, size_t ws_size,
                              hipStream_t stream) {
  const float* x  = (const float*)d_in[0];
  const int* eidx = (const int*)d_in[1];
  const float* W0 = (const float*)d_in[2];
  const float* b0 = (const float*)d_in[3];
  const float* W1 = (const float*)d_in[4];
  const float* b1 = (const float*)d_in[5];
  const float* W2 = (const float*)d_in[6];
  const float* b2 = (const float*)d_in[7];
  float* outp = (float*)d_out;

  const int N = in_sizes[0] / NFEAT;   // 100000
  const int E = in_sizes[1] / 2;       // 1600000 (divisible by 4)
  const int* src = eidx;
  const int* dst = eidx + E;
  const int NBUC = (N + BWID - 1) >> BSH;  // 196
  const int e4 = E / 4;

  // workspace layout (all chunk sizes 1KB-multiples)
  const size_t S1 = 401408;                   // > (N+1)*4
  const size_t SBK = 1024;                    // > (NBUC+1)*4
  const size_t SW = 32768;                    // 128*128*2
  const size_t SE = (size_t)E * 4;            // 6.4 MB packed edges
  const size_t SEB = (size_t)E * 8;           // 12.8 MB bucketed (dst,src)
  const size_t SH = (size_t)N * NFEAT * 2;    // 25.6 MB f16 features
  char* p = (char*)d_ws;
  float* dinv   = (float*)p;            p += S1;
  int*   rowp   = (int*)p;              p += S1;
  int*   bcnt   = (int*)p;              p += SBK;
  int*   boff   = (int*)p;              p += SBK;
  int*   gcur   = (int*)p;              p += SBK;
  unsigned short* Wt0 = (unsigned short*)p;  p += SW;  // bf16
  unsigned short* Wt1 = (unsigned short*)p;  p += SW;  // f16
  unsigned short* Wt2 = (unsigned short*)p;  p += SW;  // f16
  unsigned int* colw = (unsigned int*)p; p += SE;
  unsigned long long* ebuf = (unsigned long long*)p; p += SEB;
  unsigned short* hWb = (unsigned short*)p;  p += SH;  // f16 gather table
  unsigned short* hA  = (unsigned short*)p;  p += SH;  // f16 h
  unsigned short* hB  = (unsigned short*)p;  p += SH;  // f16 h

  int gemm_blocks = (N + 63) / 64;        // 1563
  int cbk = (e4 + 1023) / 1024;           // 391 (4096 edges/block)
  int agg_blocks = (N + 3) / 4;

  // ---- prep (wprep also zeroes bcnt) + fused {gemm0, Pass A} ----
  wprep_kernel<<<192, 256, 0, stream>>>(W0, W1, W2, Wt0, Wt1, Wt2, bcnt);
  fused_g0_hist_kernel<<<gemm_blocks + cbk, 256, 0, stream>>>(
      x, Wt0, hWb, N, gemm_blocks, (const int4*)dst, bcnt, e4, NBUC);

  // ---- bucketed CSR build ----
  scan_buckets_kernel<<<1, 256, 0, stream>>>(bcnt, boff, gcur, rowp,
                                             NBUC, N, E);
  bucket_scatter_kernel<<<cbk, 256, 0, stream>>>(
      (const int4*)src, (const int4*)dst, gcur, ebuf, e4);
  bucket_deg_kernel<<<NBUC, 256, 0, stream>>>(ebuf, boff, rowp, dinv, N);
  bucket_fill_kernel<<<NBUC, 256, 0, stream>>>(ebuf, boff, rowp, dinv,
                                               colw, N);

  // ---- layer 0 aggregate (gemm0 already done): out hA f16 ----
  aggregate_kernel<<<agg_blocks, 256, 0, stream>>>(
      hWb, rowp, colw, dinv, b0, nullptr, hA, N, 0);
  // ---- layer 1 ----
  gemm_f16_kernel<<<gemm_blocks, 256, 0, stream>>>(hA, Wt1, hWb, N);
  aggregate_kernel<<<agg_blocks, 256, 0, stream>>>(
      hWb, rowp, colw, dinv, b1, (const unsigned int*)hA, hB, N, 1);
  // ---- layer 2, write d_out f32 ----
  gemm_f16_kernel<<<gemm_blocks, 256, 0, stream>>>(hB, Wt2, hWb, N);
  aggregate_kernel<<<agg_blocks, 256, 0, stream>>>(
      hWb, rowp, colw, dinv, b2, (const unsigned int*)hB, outp, N, 2);
}